// Round 1
// baseline (1171.895 us; speedup 1.0000x reference)
//
#include <hip/hip_runtime.h>

#define RN 4
#define DIN 128
#define XSTRIDE 132   // R + DIN

// ---------------- count in-degree (once; same for both layers) -------------
__global__ void count_kernel(const int* __restrict__ ei, int E, float* __restrict__ cnt) {
    int e = blockIdx.x * 256 + threadIdx.x;
    if (e < E) atomicAdd(&cnt[ei[E + e]], 1.0f);
}

__global__ void inv_kernel(float* __restrict__ cnt, int N) {
    int n = blockIdx.x * 256 + threadIdx.x;
    if (n < N) { float c = cnt[n]; cnt[n] = (c > 0.0f) ? (1.0f / c) : 0.0f; }
}

// ---------------- per-node message: relu(sum_r coef_r (f @ Wm_r + bm_r)) ----
// Treated as (N x 384) @ (384 x 128) with LDS-staged coef-scaled features.
__global__ __launch_bounds__(256) void msg_kernel(
    const float* __restrict__ x,                   // N x 132 (roles in cols 0..3)
    const float* __restrict__ feats, int fstride, int foffset,
    const float* __restrict__ W,                   // 384 x 128 (first 3 r-slices of Wm_l)
    const float* __restrict__ b,                   // bm_l: 4 x 128
    float* __restrict__ out)                       // N x 128
{
    __shared__ float g[16][384];
    __shared__ float c[16][4];
    int tid = threadIdx.x;
    int n0 = blockIdx.x * 16;

    if (tid < 16) {
        const float* xr = x + (size_t)(n0 + tid) * XSTRIDE;
        c[tid][0] = 2.0f * xr[0];
        c[tid][1] = xr[1];
        c[tid][2] = xr[2];
    }
    __syncthreads();

    // build scaled-feature stack: 16 nodes x 128 feats
    #pragma unroll
    for (int it = 0; it < 8; ++it) {
        int idx = it * 256 + tid;            // 0..2047
        int n = idx >> 7, i = idx & 127;
        float f = feats[(size_t)(n0 + n) * fstride + foffset + i];
        g[n][i]       = c[n][0] * f;
        g[n][128 + i] = c[n][1] * f;
        g[n][256 + i] = c[n][2] * f;
    }
    __syncthreads();

    int o = tid & 127, nh = tid >> 7;
    float acc[8];
    #pragma unroll
    for (int n = 0; n < 8; ++n) acc[n] = 0.0f;
    const float* Wc = W + o;
    for (int k = 0; k < 384; k += 4) {
        float w0 = Wc[(k + 0) * 128];
        float w1 = Wc[(k + 1) * 128];
        float w2 = Wc[(k + 2) * 128];
        float w3 = Wc[(k + 3) * 128];
        #pragma unroll
        for (int n = 0; n < 8; ++n) {
            const float4 gv = *(const float4*)&g[nh * 8 + n][k];
            acc[n] += gv.x * w0 + gv.y * w1 + gv.z * w2 + gv.w * w3;
        }
    }
    #pragma unroll
    for (int n = 0; n < 8; ++n) {
        int nn = nh * 8 + n;
        float bias = c[nn][0] * b[o] + c[nn][1] * b[128 + o] + c[nn][2] * b[256 + o];
        float v = acc[n] + bias;
        out[(size_t)(n0 + nn) * 128 + o] = v > 0.0f ? v : 0.0f;
    }
}

// ---------------- edge scatter: S[dst] += M[src] ----------------------------
__global__ __launch_bounds__(256) void edge_scatter(
    const int* __restrict__ ei, int E,
    const float* __restrict__ M, float* __restrict__ S)
{
    int e = blockIdx.x * 4 + (threadIdx.x >> 6);
    int lane = threadIdx.x & 63;
    if (e >= E) return;
    int src = ei[e];
    int dst = ei[E + e];
    const float* m = M + (size_t)src * 128;
    float* s = S + (size_t)dst * 128;
    atomicAdd(&s[lane], m[lane]);
    atomicAdd(&s[lane + 64], m[lane + 64]);
}

// ---------------- scale by 1/deg -------------------------------------------
__global__ __launch_bounds__(256) void scale_kernel(
    float* __restrict__ S, const float* __restrict__ inv, int total)
{
    int idx = blockIdx.x * 256 + threadIdx.x;
    if (idx < total) S[idx] *= inv[idx >> 7];
}

// ---------------- update: relu(sum_r coef_r (cat @ Wa_r + ba_r)), row-norm --
__global__ __launch_bounds__(256) void update_kernel(
    const float* __restrict__ x,
    const float* __restrict__ feats, int fstride, int foffset,
    const float* __restrict__ aggr,                // N x 128
    const float* __restrict__ W,                   // 768 x 128 (first 3 r-slices of Wa_l)
    const float* __restrict__ b,                   // ba_l: 4 x 128
    float* __restrict__ outF)                      // N x 128
{
    __shared__ float g[16][768];
    __shared__ float c[16][4];
    __shared__ float ov[16][128];
    __shared__ float p_lds[16][16];
    __shared__ float nrm[16];
    int tid = threadIdx.x;
    int n0 = blockIdx.x * 16;

    if (tid < 16) {
        const float* xr = x + (size_t)(n0 + tid) * XSTRIDE;
        c[tid][0] = 2.0f * xr[0];
        c[tid][1] = xr[1];
        c[tid][2] = xr[2];
    }
    __syncthreads();

    #pragma unroll
    for (int it = 0; it < 16; ++it) {
        int idx = it * 256 + tid;            // 0..4095
        int n = idx >> 8, i = idx & 255;
        float v = (i < 128) ? feats[(size_t)(n0 + n) * fstride + foffset + i]
                            : aggr[(size_t)(n0 + n) * 128 + (i - 128)];
        g[n][i]       = c[n][0] * v;
        g[n][256 + i] = c[n][1] * v;
        g[n][512 + i] = c[n][2] * v;
    }
    __syncthreads();

    int o = tid & 127, nh = tid >> 7;
    float acc[8];
    #pragma unroll
    for (int n = 0; n < 8; ++n) acc[n] = 0.0f;
    const float* Wc = W + o;
    for (int k = 0; k < 768; k += 4) {
        float w0 = Wc[(k + 0) * 128];
        float w1 = Wc[(k + 1) * 128];
        float w2 = Wc[(k + 2) * 128];
        float w3 = Wc[(k + 3) * 128];
        #pragma unroll
        for (int n = 0; n < 8; ++n) {
            const float4 gv = *(const float4*)&g[nh * 8 + n][k];
            acc[n] += gv.x * w0 + gv.y * w1 + gv.z * w2 + gv.w * w3;
        }
    }
    #pragma unroll
    for (int n = 0; n < 8; ++n) {
        int nn = nh * 8 + n;
        float bias = c[nn][0] * b[o] + c[nn][1] * b[128 + o] + c[nn][2] * b[256 + o];
        float v = acc[n] + bias;
        ov[nn][o] = v > 0.0f ? v : 0.0f;
    }
    __syncthreads();
    {
        int nn2 = tid >> 4, l16 = tid & 15;
        float p = 0.0f;
        for (int o2 = l16; o2 < 128; o2 += 16) { float v = ov[nn2][o2]; p += v * v; }
        p_lds[nn2][l16] = p;
    }
    __syncthreads();
    if (tid < 16) {
        float s = 0.0f;
        #pragma unroll
        for (int k = 0; k < 16; ++k) s += p_lds[tid][k];
        nrm[tid] = 1.0f / fmaxf(sqrtf(s), 1e-12f);
    }
    __syncthreads();
    #pragma unroll
    for (int it = 0; it < 8; ++it) {
        int idx = it * 256 + tid;
        int n = idx >> 7, oo = idx & 127;
        outF[(size_t)(n0 + n) * 128 + oo] = ov[n][oo] * nrm[n];
    }
}

// ---------------- final: z = F@W1+b1; logits = z@W2+b2; log_softmax ---------
__global__ __launch_bounds__(256) void final_kernel(
    const float* __restrict__ F,                   // N x 128
    const float* __restrict__ W1, const float* __restrict__ b1,
    const float* __restrict__ W2, const float* __restrict__ b2,
    float* __restrict__ out)                       // N x 40
{
    __shared__ float f[16][128];
    __shared__ float z[16][128];
    __shared__ float lg[16][40];
    __shared__ float mred[16], sred[16];
    int tid = threadIdx.x;
    int n0 = blockIdx.x * 16;

    #pragma unroll
    for (int it = 0; it < 8; ++it) {
        int idx = it * 256 + tid;
        f[idx >> 7][idx & 127] = F[(size_t)n0 * 128 + idx];
    }
    __syncthreads();

    int o = tid & 127, nh = tid >> 7;
    float acc[8];
    #pragma unroll
    for (int n = 0; n < 8; ++n) acc[n] = 0.0f;
    const float* Wc = W1 + o;
    for (int k = 0; k < 128; k += 4) {
        float w0 = Wc[(k + 0) * 128];
        float w1 = Wc[(k + 1) * 128];
        float w2 = Wc[(k + 2) * 128];
        float w3 = Wc[(k + 3) * 128];
        #pragma unroll
        for (int n = 0; n < 8; ++n) {
            const float4 fv = *(const float4*)&f[nh * 8 + n][k];
            acc[n] += fv.x * w0 + fv.y * w1 + fv.z * w2 + fv.w * w3;
        }
    }
    #pragma unroll
    for (int n = 0; n < 8; ++n) z[nh * 8 + n][o] = acc[n] + b1[o];
    __syncthreads();

    for (int t = tid; t < 640; t += 256) {
        int n = t / 40, j = t % 40;
        float a = b2[j];
        for (int k = 0; k < 128; ++k) a += z[n][k] * W2[k * 40 + j];
        lg[n][j] = a;
    }
    __syncthreads();

    if (tid < 16) {
        float m = -1e30f;
        #pragma unroll
        for (int j = 0; j < 40; ++j) m = fmaxf(m, lg[tid][j]);
        float s = 0.0f;
        #pragma unroll
        for (int j = 0; j < 40; ++j) s += __expf(lg[tid][j] - m);
        mred[tid] = m;
        sred[tid] = __logf(s);
    }
    __syncthreads();

    for (int t = tid; t < 640; t += 256) {
        int n = t / 40, j = t % 40;
        out[(size_t)(n0 + n) * 40 + j] = lg[n][j] - mred[n] - sred[n];
    }
}

extern "C" void kernel_launch(void* const* d_in, const int* in_sizes, int n_in,
                              void* d_out, int out_size, void* d_ws, size_t ws_size,
                              hipStream_t stream) {
    const float* x  = (const float*)d_in[0];
    const int*   ei = (const int*)d_in[1];
    const float* Wm = (const float*)d_in[2];
    const float* bm = (const float*)d_in[3];
    const float* Wa = (const float*)d_in[4];
    const float* ba = (const float*)d_in[5];
    const float* W1 = (const float*)d_in[6];
    const float* b1 = (const float*)d_in[7];
    const float* W2 = (const float*)d_in[8];
    const float* b2 = (const float*)d_in[9];
    float* out = (float*)d_out;

    const int N = in_sizes[0] / XSTRIDE;   // 40000
    const int E = in_sizes[1] / 2;         // 480000

    float* M   = (float*)d_ws;             // N*128  (msg; reused as layer-2 feats out)
    float* S   = M + (size_t)N * 128;      // N*128  (ssum -> aggr)
    float* cnt = S + (size_t)N * 128;      // N      (deg -> 1/deg)
    float* F1  = cnt + N;                  // N*128  (layer-1 feats out)

    // in-degree reciprocal (layer-independent)
    hipMemsetAsync(cnt, 0, (size_t)N * sizeof(float), stream);
    count_kernel<<<(E + 255) / 256, 256, 0, stream>>>(ei, E, cnt);
    inv_kernel<<<(N + 255) / 256, 256, 0, stream>>>(cnt, N);

    const int nblk = N / 16;               // 2500
    for (int l = 0; l < 2; ++l) {
        const float* fp = (l == 0) ? x : F1;
        int fs = (l == 0) ? XSTRIDE : 128;
        int fo = (l == 0) ? RN : 0;
        float* outF = (l == 0) ? F1 : M;

        msg_kernel<<<nblk, 256, 0, stream>>>(x, fp, fs, fo,
                                             Wm + (size_t)l * 4 * 128 * 128,
                                             bm + (size_t)l * 4 * 128, M);
        hipMemsetAsync(S, 0, (size_t)N * 128 * sizeof(float), stream);
        edge_scatter<<<(E + 3) / 4, 256, 0, stream>>>(ei, E, M, S);
        scale_kernel<<<(N * 128 + 255) / 256, 256, 0, stream>>>(S, cnt, N * 128);
        update_kernel<<<nblk, 256, 0, stream>>>(x, fp, fs, fo, S,
                                                Wa + (size_t)l * 4 * 256 * 128,
                                                ba + (size_t)l * 4 * 128, outF);
    }

    final_kernel<<<nblk, 256, 0, stream>>>(M, W1, b1, W2, b2, out);
}

// Round 2
// 672.447 us; speedup vs baseline: 1.7427x; 1.7427x over previous
//
#include <hip/hip_runtime.h>

#define RN 4
#define XSTRIDE 132   // R + DIN

// ---------------- CSR build ------------------------------------------------
__global__ void count_kernel(const int* __restrict__ ei, int E, int* __restrict__ cnt) {
    int e = blockIdx.x * 256 + threadIdx.x;
    if (e < E) atomicAdd(&cnt[ei[E + e]], 1);
}

__global__ void scanA(const int* __restrict__ cnt, int N, int* __restrict__ bsums) {
    __shared__ int s[256];
    int t = threadIdx.x, n = blockIdx.x * 256 + t;
    s[t] = (n < N) ? cnt[n] : 0;
    __syncthreads();
    for (int off = 128; off > 0; off >>= 1) {
        if (t < off) s[t] += s[t + off];
        __syncthreads();
    }
    if (t == 0) bsums[blockIdx.x] = s[0];
}

__global__ void scanB(int* __restrict__ bsums, int nb) {
    __shared__ int s[256];
    int t = threadIdx.x;
    int v = (t < nb) ? bsums[t] : 0;
    s[t] = v; __syncthreads();
    for (int off = 1; off < 256; off <<= 1) {
        int add = (t >= off) ? s[t - off] : 0;
        __syncthreads();
        s[t] += add;
        __syncthreads();
    }
    if (t < nb) bsums[t] = s[t] - v;   // exclusive
}

__global__ void scanC(const int* __restrict__ cnt, int N,
                      const int* __restrict__ bsums, int* __restrict__ offs) {
    __shared__ int s[256];
    int t = threadIdx.x, n = blockIdx.x * 256 + t;
    int v = (n < N) ? cnt[n] : 0;
    s[t] = v; __syncthreads();
    for (int off = 1; off < 256; off <<= 1) {
        int add = (t >= off) ? s[t - off] : 0;
        __syncthreads();
        s[t] += add;
        __syncthreads();
    }
    if (n < N) {
        offs[n] = bsums[blockIdx.x] + s[t] - v;
        if (n == N - 1) offs[N] = bsums[blockIdx.x] + s[t];
    }
}

__global__ void fill_kernel(const int* __restrict__ ei, int E,
                            const int* __restrict__ offs, int* __restrict__ fc,
                            int* __restrict__ csr) {
    int e = blockIdx.x * 256 + threadIdx.x;
    if (e < E) {
        int dst = ei[E + e];
        int p = offs[dst] + atomicAdd(&fc[dst], 1);
        csr[p] = ei[e];
    }
}

// ---------------- aggregate: S[n] = mean over in-edges of M[src] ------------
__global__ __launch_bounds__(256) void agg_kernel(
    const int* __restrict__ csr, const int* __restrict__ offs,
    const float* __restrict__ M, float* __restrict__ S, int N)
{
    int node = blockIdx.x * 4 + (threadIdx.x >> 6);
    int lane = threadIdx.x & 63;
    if (node >= N) return;
    int lo = offs[node], hi = offs[node + 1];
    float2 acc = {0.0f, 0.0f};
    int e = lo;
    for (; e + 1 < hi; e += 2) {
        int s0 = csr[e], s1 = csr[e + 1];
        const float2 a = *(const float2*)(M + (size_t)s0 * 128 + lane * 2);
        const float2 b = *(const float2*)(M + (size_t)s1 * 128 + lane * 2);
        acc.x += a.x + b.x; acc.y += a.y + b.y;
    }
    if (e < hi) {
        int s0 = csr[e];
        const float2 a = *(const float2*)(M + (size_t)s0 * 128 + lane * 2);
        acc.x += a.x; acc.y += a.y;
    }
    float inv = (hi > lo) ? 1.0f / (float)(hi - lo) : 0.0f;
    float2 o; o.x = acc.x * inv; o.y = acc.y * inv;
    *(float2*)(S + (size_t)node * 128 + lane * 2) = o;
}

// ---------------- role-weighted GEMM: out = relu(sum_r c_r (v @ W_r + b_r)) -
// tile 32 nodes x 128 outputs; wave = 8 nodes, lane = output pair (o, o+64).
// 3 per-role accumulators instead of coef-prescaled LDS: all LDS reads are
// wave-broadcast (zero bank conflicts), 192 FMA per 8 ds_read_b128.
template<int KV, bool NORM>
__global__ __launch_bounds__(256) void gemm_role(
    const float* __restrict__ x,
    const float* __restrict__ feats, int fstride, int foffset,
    const float* __restrict__ aggr,                // used when KV==256
    const float* __restrict__ W,                   // [3][KV][128] contiguous
    const float* __restrict__ b,                   // [4][128]
    float* __restrict__ outF)                      // N x 128
{
    __shared__ float v[32][KV];
    __shared__ float c[32][3];
    int tid = threadIdx.x;
    int n0 = blockIdx.x * 32;

    if (tid < 32) {
        const float* xr = x + (size_t)(n0 + tid) * XSTRIDE;
        c[tid][0] = 2.0f * xr[0];
        c[tid][1] = xr[1];
        c[tid][2] = xr[2];
    }
    constexpr int TOT = 32 * KV / 256;
    #pragma unroll
    for (int it = 0; it < TOT; ++it) {
        int idx = it * 256 + tid;
        int n, k;
        if (KV == 128) { n = idx >> 7; k = idx & 127; }
        else           { n = idx >> 8; k = idx & 255; }
        float val;
        if (KV == 128) {
            val = feats[(size_t)(n0 + n) * fstride + foffset + k];
        } else {
            val = (k < 128) ? feats[(size_t)(n0 + n) * fstride + foffset + k]
                            : aggr[(size_t)(n0 + n) * 128 + (k - 128)];
        }
        v[n][k] = val;
    }
    __syncthreads();

    int wv = tid >> 6, lane = tid & 63;
    int nb = wv * 8;

    float acc[8][2][3];
    #pragma unroll
    for (int n = 0; n < 8; ++n)
        #pragma unroll
        for (int j = 0; j < 2; ++j)
            #pragma unroll
            for (int r = 0; r < 3; ++r) acc[n][j][r] = 0.0f;

    const float* wp[6];
    #pragma unroll
    for (int r = 0; r < 3; ++r) {
        wp[r * 2]     = W + (size_t)r * KV * 128 + lane;
        wp[r * 2 + 1] = W + (size_t)r * KV * 128 + lane + 64;
    }
    float bb[2][3];
    #pragma unroll
    for (int r = 0; r < 3; ++r) {
        bb[0][r] = b[r * 128 + lane];
        bb[1][r] = b[r * 128 + lane + 64];
    }

    for (int k = 0; k < KV; k += 4) {
        float wr[3][2][4];
        #pragma unroll
        for (int r = 0; r < 3; ++r)
            #pragma unroll
            for (int j = 0; j < 2; ++j)
                #pragma unroll
                for (int kk = 0; kk < 4; ++kk)
                    wr[r][j][kk] = wp[r * 2 + j][kk * 128];
        #pragma unroll
        for (int i = 0; i < 6; ++i) wp[i] += 512;
        #pragma unroll
        for (int n = 0; n < 8; ++n) {
            float4 a = *(const float4*)&v[nb + n][k];
            #pragma unroll
            for (int j = 0; j < 2; ++j)
                #pragma unroll
                for (int r = 0; r < 3; ++r)
                    acc[n][j][r] += a.x * wr[r][j][0] + a.y * wr[r][j][1]
                                  + a.z * wr[r][j][2] + a.w * wr[r][j][3];
        }
    }

    #pragma unroll
    for (int n = 0; n < 8; ++n) {
        int nn = nb + n;
        float c0 = c[nn][0], c1 = c[nn][1], c2 = c[nn][2];
        float v0 = c0 * (acc[n][0][0] + bb[0][0]) + c1 * (acc[n][0][1] + bb[0][1])
                 + c2 * (acc[n][0][2] + bb[0][2]);
        float v1 = c0 * (acc[n][1][0] + bb[1][0]) + c1 * (acc[n][1][1] + bb[1][1])
                 + c2 * (acc[n][1][2] + bb[1][2]);
        v0 = v0 > 0.0f ? v0 : 0.0f;
        v1 = v1 > 0.0f ? v1 : 0.0f;
        if (NORM) {
            float ss = v0 * v0 + v1 * v1;
            #pragma unroll
            for (int m = 1; m < 64; m <<= 1) ss += __shfl_xor(ss, m, 64);
            float inv = 1.0f / fmaxf(sqrtf(ss), 1e-12f);
            v0 *= inv; v1 *= inv;
        }
        outF[(size_t)(n0 + nn) * 128 + lane]      = v0;
        outF[(size_t)(n0 + nn) * 128 + lane + 64] = v1;
    }
}

// ---------------- final: z = F@W1+b1; logits = z@W2+b2; log_softmax ---------
__global__ __launch_bounds__(256) void final_kernel(
    const float* __restrict__ F,
    const float* __restrict__ W1, const float* __restrict__ b1,
    const float* __restrict__ W2, const float* __restrict__ b2,
    float* __restrict__ out)
{
    __shared__ float f[16][128];
    __shared__ float z[16][128];
    __shared__ float lg[16][40];
    __shared__ float mred[16], sred[16];
    int tid = threadIdx.x;
    int n0 = blockIdx.x * 16;

    #pragma unroll
    for (int it = 0; it < 8; ++it) {
        int idx = it * 256 + tid;
        f[idx >> 7][idx & 127] = F[(size_t)n0 * 128 + idx];
    }
    __syncthreads();

    int o = tid & 127, nh = tid >> 7;
    float acc[8];
    #pragma unroll
    for (int n = 0; n < 8; ++n) acc[n] = 0.0f;
    const float* Wc = W1 + o;
    for (int k = 0; k < 128; k += 4) {
        float w0 = Wc[(k + 0) * 128];
        float w1 = Wc[(k + 1) * 128];
        float w2 = Wc[(k + 2) * 128];
        float w3 = Wc[(k + 3) * 128];
        #pragma unroll
        for (int n = 0; n < 8; ++n) {
            const float4 fv = *(const float4*)&f[nh * 8 + n][k];
            acc[n] += fv.x * w0 + fv.y * w1 + fv.z * w2 + fv.w * w3;
        }
    }
    #pragma unroll
    for (int n = 0; n < 8; ++n) z[nh * 8 + n][o] = acc[n] + b1[o];
    __syncthreads();

    for (int t = tid; t < 640; t += 256) {
        int n = t / 40, j = t % 40;
        float a = b2[j];
        for (int k = 0; k < 128; ++k) a += z[n][k] * W2[k * 40 + j];
        lg[n][j] = a;
    }
    __syncthreads();

    if (tid < 16) {
        float m = -1e30f;
        #pragma unroll
        for (int j = 0; j < 40; ++j) m = fmaxf(m, lg[tid][j]);
        float s = 0.0f;
        #pragma unroll
        for (int j = 0; j < 40; ++j) s += __expf(lg[tid][j] - m);
        mred[tid] = m;
        sred[tid] = __logf(s);
    }
    __syncthreads();

    for (int t = tid; t < 640; t += 256) {
        int n = t / 40, j = t % 40;
        out[(size_t)(n0 + n) * 40 + j] = lg[n][j] - mred[n] - sred[n];
    }
}

extern "C" void kernel_launch(void* const* d_in, const int* in_sizes, int n_in,
                              void* d_out, int out_size, void* d_ws, size_t ws_size,
                              hipStream_t stream) {
    const float* x  = (const float*)d_in[0];
    const int*   ei = (const int*)d_in[1];
    const float* Wm = (const float*)d_in[2];
    const float* bm = (const float*)d_in[3];
    const float* Wa = (const float*)d_in[4];
    const float* ba = (const float*)d_in[5];
    const float* W1 = (const float*)d_in[6];
    const float* b1 = (const float*)d_in[7];
    const float* W2 = (const float*)d_in[8];
    const float* b2 = (const float*)d_in[9];
    float* out = (float*)d_out;

    const int N = in_sizes[0] / XSTRIDE;   // 40000
    const int E = in_sizes[1] / 2;         // 480000
    const int NB = (N + 255) / 256;        // 157

    float* M   = (float*)d_ws;             // N*128
    float* S   = M + (size_t)N * 128;      // N*128
    float* F1  = S + (size_t)N * 128;      // N*128
    int* cnt   = (int*)(F1 + (size_t)N * 128); // N
    int* offs  = cnt + N;                  // N+1
    int* csr   = offs + N + 1;             // E
    int* bsums = csr + E;                  // NB

    // ---- CSR build (edges identical for both layers; rebuilt every call) ----
    hipMemsetAsync(cnt, 0, (size_t)N * sizeof(int), stream);
    count_kernel<<<(E + 255) / 256, 256, 0, stream>>>(ei, E, cnt);
    scanA<<<NB, 256, 0, stream>>>(cnt, N, bsums);
    scanB<<<1, 256, 0, stream>>>(bsums, NB);
    scanC<<<NB, 256, 0, stream>>>(cnt, N, bsums, offs);
    hipMemsetAsync(cnt, 0, (size_t)N * sizeof(int), stream);  // reuse as fill ctr
    fill_kernel<<<(E + 255) / 256, 256, 0, stream>>>(ei, E, offs, cnt, csr);

    const int gblk = N / 32;               // 1250
    for (int l = 0; l < 2; ++l) {
        const float* fp = (l == 0) ? x : F1;
        int fs = (l == 0) ? XSTRIDE : 128;
        int fo = (l == 0) ? RN : 0;
        float* outF = (l == 0) ? F1 : M;

        gemm_role<128, false><<<gblk, 256, 0, stream>>>(
            x, fp, fs, fo, nullptr,
            Wm + (size_t)l * 4 * 128 * 128, bm + (size_t)l * 4 * 128, M);
        agg_kernel<<<(N + 3) / 4, 256, 0, stream>>>(csr, offs, M, S, N);
        gemm_role<256, true><<<gblk, 256, 0, stream>>>(
            x, fp, fs, fo, S,
            Wa + (size_t)l * 4 * 256 * 128, ba + (size_t)l * 4 * 128, outF);
    }

    final_kernel<<<N / 16, 256, 0, stream>>>(M, W1, b1, W2, b2, out);
}

// Round 3
// 462.927 us; speedup vs baseline: 2.5315x; 1.4526x over previous
//
#include <hip/hip_runtime.h>

#define RN 4
#define XSTRIDE 132   // R + DIN

typedef float  frag_cd __attribute__((ext_vector_type(4)));
typedef short  frag_ab __attribute__((ext_vector_type(8)));

__device__ __forceinline__ ushort f2bf(float f) {
    uint u = __float_as_uint(f);
    u += 0x7FFF + ((u >> 16) & 1);        // RNE
    return (ushort)(u >> 16);
}
__device__ __forceinline__ float bf2f(ushort h) {
    return __uint_as_float(((uint)h) << 16);
}

// ---------------- CSR build ------------------------------------------------
__global__ void count_kernel(const int* __restrict__ ei, int E, int* __restrict__ cnt) {
    int e = blockIdx.x * 256 + threadIdx.x;
    if (e < E) atomicAdd(&cnt[ei[E + e]], 1);
}

__global__ void scanA(const int* __restrict__ cnt, int N, int* __restrict__ bsums) {
    __shared__ int s[256];
    int t = threadIdx.x, n = blockIdx.x * 256 + t;
    s[t] = (n < N) ? cnt[n] : 0;
    __syncthreads();
    for (int off = 128; off > 0; off >>= 1) {
        if (t < off) s[t] += s[t + off];
        __syncthreads();
    }
    if (t == 0) bsums[blockIdx.x] = s[0];
}

__global__ void scanB(int* __restrict__ bsums, int nb) {
    __shared__ int s[256];
    int t = threadIdx.x;
    int v = (t < nb) ? bsums[t] : 0;
    s[t] = v; __syncthreads();
    for (int off = 1; off < 256; off <<= 1) {
        int add = (t >= off) ? s[t - off] : 0;
        __syncthreads();
        s[t] += add;
        __syncthreads();
    }
    if (t < nb) bsums[t] = s[t] - v;   // exclusive
}

__global__ void scanC(const int* __restrict__ cnt, int N,
                      const int* __restrict__ bsums, int* __restrict__ offs) {
    __shared__ int s[256];
    int t = threadIdx.x, n = blockIdx.x * 256 + t;
    int v = (n < N) ? cnt[n] : 0;
    s[t] = v; __syncthreads();
    for (int off = 1; off < 256; off <<= 1) {
        int add = (t >= off) ? s[t - off] : 0;
        __syncthreads();
        s[t] += add;
        __syncthreads();
    }
    if (n < N) {
        offs[n] = bsums[blockIdx.x] + s[t] - v;
        if (n == N - 1) offs[N] = bsums[blockIdx.x] + s[t];
    }
}

__global__ void fill_kernel(const int* __restrict__ ei, int E,
                            const int* __restrict__ offs, int* __restrict__ fc,
                            int* __restrict__ csr) {
    int e = blockIdx.x * 256 + threadIdx.x;
    if (e < E) {
        int dst = ei[E + e];
        int p = offs[dst] + atomicAdd(&fc[dst], 1);
        csr[p] = ei[e];
    }
}

// ---------------- weight pre-convert: fp32 [L][4][K][128] (r<3) ------------
// -> transposed bf16 hi/lo planes [l*3+r][col][k]
__global__ void conv_w(const float* __restrict__ W, ushort* __restrict__ Th,
                       ushort* __restrict__ Tl, int K, int total) {
    int id = blockIdx.x * 256 + threadIdx.x;
    if (id >= total) return;
    int per = K * 128;
    int lr = id / per;              // 0..5  (l*3+r)
    int l = lr / 3, r = lr - l * 3;
    int rem = id - lr * per;
    int k = rem >> 7;
    int col = rem & 127;
    float v = W[(((size_t)l * 4 + r) * K + k) * 128 + col];
    ushort h = f2bf(v);
    size_t dst = ((size_t)lr * 128 + col) * K + k;
    Th[dst] = h;
    Tl[dst] = f2bf(v - bf2f(h));
}

// ---------------- aggregate: S[n] = mean over in-edges of Mb[src] (bf16) ----
__global__ __launch_bounds__(256) void agg_kernel(
    const int* __restrict__ csr, const int* __restrict__ offs,
    const ushort* __restrict__ Mb, float* __restrict__ S, int N)
{
    int node = blockIdx.x * 4 + (threadIdx.x >> 6);
    int lane = threadIdx.x & 63;
    if (node >= N) return;
    int lo = offs[node], hi = offs[node + 1];
    const uint* M32 = (const uint*)Mb;
    float a0 = 0.0f, a1 = 0.0f;
    int e = lo;
    for (; e + 1 < hi; e += 2) {
        uint u = M32[(size_t)csr[e]     * 64 + lane];
        uint v = M32[(size_t)csr[e + 1] * 64 + lane];
        a0 += __uint_as_float(u << 16) + __uint_as_float(v << 16);
        a1 += __uint_as_float(u & 0xFFFF0000u) + __uint_as_float(v & 0xFFFF0000u);
    }
    if (e < hi) {
        uint u = M32[(size_t)csr[e] * 64 + lane];
        a0 += __uint_as_float(u << 16);
        a1 += __uint_as_float(u & 0xFFFF0000u);
    }
    float inv = (hi > lo) ? 1.0f / (float)(hi - lo) : 0.0f;
    float2 o; o.x = a0 * inv; o.y = a1 * inv;
    *(float2*)(S + (size_t)node * 128 + lane * 2) = o;
}

// ---------------- MFMA role-weighted GEMM ----------------------------------
// out[n][o] = relu( sum_r c_r[n] * ( (v[n] @ W_r)[o] + b_r[o] ) ), opt row-norm.
// Block: 64 nodes x 128 cols, 4 waves; wave w: 64 nodes x cols [32w,32w+32).
// bf16 hi/lo split: C_r += Ah*Bh + Ah*Bl + Al*Bh  (~fp32 accuracy).
// A staged fp32->hi/lo in LDS per 32-k chunk; B copied from pre-converted
// transposed planes. MFMA 16x16x32: A[m=lane&15][k=q*8+j], B[k=q*8+j][n=lane&15],
// C/D col=lane&15, row=q*4+reg.
template<int KV, bool NORM>
__global__ __launch_bounds__(256) void gemm_mfma(
    const float* __restrict__ x,
    const float* __restrict__ feats, int fstride, int foffset,
    const float* __restrict__ aggr,                 // KV==256 only
    const ushort* __restrict__ Wh,                  // [3][128][KV]
    const ushort* __restrict__ Wl,
    const float* __restrict__ bias,                 // [4][128]
    float* __restrict__ outF,                       // NORM: fp32 N x 128
    ushort* __restrict__ outB)                      // !NORM: bf16 N x 128
{
    __shared__ ushort Ah[64][40];
    __shared__ ushort Al[64][40];
    __shared__ ushort Bh[128][40];
    __shared__ ushort Bl[128][40];
    __shared__ float  cc[64][3];
    __shared__ float  ov[64][132];
    __shared__ float  red[64][4];

    const int tid = threadIdx.x;
    const int n0 = blockIdx.x * 64;
    const int lane = tid & 63;
    const int wv = tid >> 6;
    const int q = lane >> 4;
    const int lb = lane & 15;
    const int w32 = wv * 32;

    if (tid < 64) {
        const float* xr = x + (size_t)(n0 + tid) * XSTRIDE;
        cc[tid][0] = 2.0f * xr[0];
        cc[tid][1] = xr[1];
        cc[tid][2] = xr[2];
    }

    frag_cd acc[3][4][2];
    #pragma unroll
    for (int r = 0; r < 3; ++r)
        #pragma unroll
        for (int nt = 0; nt < 4; ++nt)
            #pragma unroll
            for (int ct = 0; ct < 2; ++ct)
                acc[r][nt][ct] = (frag_cd){0.f, 0.f, 0.f, 0.f};

    const int NCH = KV / 32;
    #pragma unroll
    for (int r = 0; r < 3; ++r) {
        for (int ch = 0; ch < NCH; ++ch) {
            __syncthreads();
            const int k0 = ch * 32;
            { // stage A (fp32 -> hi/lo bf16)
                int kk = tid & 31;
                int nb = tid >> 5;
                #pragma unroll
                for (int it = 0; it < 8; ++it) {
                    int n = it * 8 + nb;
                    float v;
                    if (KV == 128) {
                        v = feats[(size_t)(n0 + n) * fstride + foffset + k0 + kk];
                    } else {
                        v = (k0 < 128)
                          ? feats[(size_t)(n0 + n) * fstride + foffset + k0 + kk]
                          : aggr[(size_t)(n0 + n) * 128 + (k0 - 128) + kk];
                    }
                    ushort h = f2bf(v);
                    Ah[n][kk] = h;
                    Al[n][kk] = f2bf(v - bf2f(h));
                }
            }
            { // stage B (copy pre-converted planes)
                int col = tid >> 1, half = tid & 1;
                size_t off = ((size_t)(r * 128 + col)) * KV + k0 + half * 16;
                const uint4* ph = (const uint4*)(Wh + off);
                const uint4* pl = (const uint4*)(Wl + off);
                uint4* dh = (uint4*)&Bh[col][half * 16];
                uint4* dl = (uint4*)&Bl[col][half * 16];
                dh[0] = ph[0]; dh[1] = ph[1];
                dl[0] = pl[0]; dl[1] = pl[1];
            }
            __syncthreads();

            frag_ab aH[4], aL[4];
            #pragma unroll
            for (int nt = 0; nt < 4; ++nt) {
                aH[nt] = *(const frag_ab*)&Ah[nt * 16 + lb][q * 8];
                aL[nt] = *(const frag_ab*)&Al[nt * 16 + lb][q * 8];
            }
            #pragma unroll
            for (int ct = 0; ct < 2; ++ct) {
                int col = w32 + ct * 16 + lb;
                frag_ab bH = *(const frag_ab*)&Bh[col][q * 8];
                frag_ab bL = *(const frag_ab*)&Bl[col][q * 8];
                #pragma unroll
                for (int nt = 0; nt < 4; ++nt) {
                    frag_cd t = acc[r][nt][ct];
                    t = __builtin_amdgcn_mfma_f32_16x16x32_bf16(aH[nt], bH, t, 0, 0, 0);
                    t = __builtin_amdgcn_mfma_f32_16x16x32_bf16(aH[nt], bL, t, 0, 0, 0);
                    t = __builtin_amdgcn_mfma_f32_16x16x32_bf16(aL[nt], bH, t, 0, 0, 0);
                    acc[r][nt][ct] = t;
                }
            }
        }
    }

    // ---- epilogue: combine roles + bias, relu, (norm), store ----
    #pragma unroll
    for (int ct = 0; ct < 2; ++ct) {
        int col = w32 + ct * 16 + lb;
        float b0 = bias[col], b1 = bias[128 + col], b2 = bias[256 + col];
        #pragma unroll
        for (int nt = 0; nt < 4; ++nt) {
            #pragma unroll
            for (int rg = 0; rg < 4; ++rg) {
                int row = nt * 16 + q * 4 + rg;
                float v = cc[row][0] * (acc[0][nt][ct][rg] + b0)
                        + cc[row][1] * (acc[1][nt][ct][rg] + b1)
                        + cc[row][2] * (acc[2][nt][ct][rg] + b2);
                v = fmaxf(v, 0.0f);
                if (NORM) ov[row][col] = v;
                else      outB[(size_t)(n0 + row) * 128 + col] = f2bf(v);
            }
        }
    }
    if (NORM) {
        __syncthreads();
        int row = tid & 63, qq = tid >> 6;
        float s = 0.0f;
        #pragma unroll
        for (int j = 0; j < 8; ++j) {
            float4 vv = *(const float4*)&ov[row][qq * 32 + j * 4];
            s += vv.x * vv.x + vv.y * vv.y + vv.z * vv.z + vv.w * vv.w;
        }
        red[row][qq] = s;
        __syncthreads();
        if (qq == 0) {
            float t = red[row][0] + red[row][1] + red[row][2] + red[row][3];
            red[row][0] = 1.0f / fmaxf(sqrtf(t), 1e-12f);
        }
        __syncthreads();
        float inv = red[row][0];
        #pragma unroll
        for (int j = 0; j < 8; ++j) {
            float4 vv = *(const float4*)&ov[row][qq * 32 + j * 4];
            vv.x *= inv; vv.y *= inv; vv.z *= inv; vv.w *= inv;
            *(float4*)&outF[(size_t)(n0 + row) * 128 + qq * 32 + j * 4] = vv;
        }
    }
}

// ---------------- final: z = F@W1+b1; logits = z@W2+b2; log_softmax ---------
__global__ __launch_bounds__(256) void final_kernel(
    const float* __restrict__ F,
    const float* __restrict__ W1, const float* __restrict__ b1,
    const float* __restrict__ W2, const float* __restrict__ b2,
    float* __restrict__ out)
{
    __shared__ float f[16][128];
    __shared__ float z[16][128];
    __shared__ float lg[16][40];
    __shared__ float mred[16], sred[16];
    int tid = threadIdx.x;
    int n0 = blockIdx.x * 16;

    #pragma unroll
    for (int it = 0; it < 8; ++it) {
        int idx = it * 256 + tid;
        f[idx >> 7][idx & 127] = F[(size_t)n0 * 128 + idx];
    }
    __syncthreads();

    int o = tid & 127, nh = tid >> 7;
    float acc[8];
    #pragma unroll
    for (int n = 0; n < 8; ++n) acc[n] = 0.0f;
    const float* Wc = W1 + o;
    for (int k = 0; k < 128; k += 4) {
        float w0 = Wc[(k + 0) * 128];
        float w1 = Wc[(k + 1) * 128];
        float w2 = Wc[(k + 2) * 128];
        float w3 = Wc[(k + 3) * 128];
        #pragma unroll
        for (int n = 0; n < 8; ++n) {
            const float4 fv = *(const float4*)&f[nh * 8 + n][k];
            acc[n] += fv.x * w0 + fv.y * w1 + fv.z * w2 + fv.w * w3;
        }
    }
    #pragma unroll
    for (int n = 0; n < 8; ++n) z[nh * 8 + n][o] = acc[n] + b1[o];
    __syncthreads();

    for (int t = tid; t < 640; t += 256) {
        int n = t / 40, j = t % 40;
        float a = b2[j];
        for (int k = 0; k < 128; ++k) a += z[n][k] * W2[k * 40 + j];
        lg[n][j] = a;
    }
    __syncthreads();

    if (tid < 16) {
        float m = -1e30f;
        #pragma unroll
        for (int j = 0; j < 40; ++j) m = fmaxf(m, lg[tid][j]);
        float s = 0.0f;
        #pragma unroll
        for (int j = 0; j < 40; ++j) s += __expf(lg[tid][j] - m);
        mred[tid] = m;
        sred[tid] = __logf(s);
    }
    __syncthreads();

    for (int t = tid; t < 640; t += 256) {
        int n = t / 40, j = t % 40;
        out[(size_t)(n0 + n) * 40 + j] = lg[n][j] - mred[n] - sred[n];
    }
}

extern "C" void kernel_launch(void* const* d_in, const int* in_sizes, int n_in,
                              void* d_out, int out_size, void* d_ws, size_t ws_size,
                              hipStream_t stream) {
    const float* x  = (const float*)d_in[0];
    const int*   ei = (const int*)d_in[1];
    const float* Wm = (const float*)d_in[2];
    const float* bm = (const float*)d_in[3];
    const float* Wa = (const float*)d_in[4];
    const float* ba = (const float*)d_in[5];
    const float* W1 = (const float*)d_in[6];
    const float* b1 = (const float*)d_in[7];
    const float* W2 = (const float*)d_in[8];
    const float* b2 = (const float*)d_in[9];
    float* out = (float*)d_out;

    const int N = in_sizes[0] / XSTRIDE;   // 40000
    const int E = in_sizes[1] / 2;         // 480000
    const int NB = (N + 255) / 256;        // 157

    // workspace carve (16B-aligned throughout)
    ushort* Mb   = (ushort*)d_ws;                       // N*128 bf16 (msg)
    float*  S    = (float*)(Mb + (size_t)N * 128);      // N*128 f32
    float*  F1   = S + (size_t)N * 128;                 // N*128 f32
    ushort* WmTh = (ushort*)(F1 + (size_t)N * 128);     // 6*128*128
    ushort* WmTl = WmTh + 6 * 128 * 128;
    ushort* WaTh = WmTl + 6 * 128 * 128;                // 6*128*256
    ushort* WaTl = WaTh + 6 * 128 * 256;
    int* cnt   = (int*)(WaTl + 6 * 128 * 256);
    int* offs  = cnt + N;
    int* csr   = offs + N + 1;
    int* bsums = csr + E;

    // ---- weight pre-convert (bf16 hi/lo, transposed [col][k]) ----
    conv_w<<<(6 * 128 * 128 + 255) / 256, 256, 0, stream>>>(Wm, WmTh, WmTl, 128, 6 * 128 * 128);
    conv_w<<<(6 * 128 * 256 + 255) / 256, 256, 0, stream>>>(Wa, WaTh, WaTl, 256, 6 * 128 * 256);

    // ---- CSR build ----
    hipMemsetAsync(cnt, 0, (size_t)N * sizeof(int), stream);
    count_kernel<<<(E + 255) / 256, 256, 0, stream>>>(ei, E, cnt);
    scanA<<<NB, 256, 0, stream>>>(cnt, N, bsums);
    scanB<<<1, 256, 0, stream>>>(bsums, NB);
    scanC<<<NB, 256, 0, stream>>>(cnt, N, bsums, offs);
    hipMemsetAsync(cnt, 0, (size_t)N * sizeof(int), stream);
    fill_kernel<<<(E + 255) / 256, 256, 0, stream>>>(ei, E, offs, cnt, csr);

    const int gblk = N / 64;               // 625
    for (int l = 0; l < 2; ++l) {
        const float* fp = (l == 0) ? x : F1;
        int fs = (l == 0) ? XSTRIDE : 128;
        int fo = (l == 0) ? RN : 0;

        gemm_mfma<128, false><<<gblk, 256, 0, stream>>>(
            x, fp, fs, fo, nullptr,
            WmTh + (size_t)l * 3 * 128 * 128, WmTl + (size_t)l * 3 * 128 * 128,
            bm + (size_t)l * 4 * 128, nullptr, Mb);
        agg_kernel<<<(N + 3) / 4, 256, 0, stream>>>(csr, offs, Mb, S, N);
        gemm_mfma<256, true><<<gblk, 256, 0, stream>>>(
            x, fp, fs, fo, S,
            WaTh + (size_t)l * 3 * 128 * 256, WaTl + (size_t)l * 3 * 128 * 256,
            ba + (size_t)l * 4 * 128, F1, nullptr);   // in-place F1: block reads own rows before write
    }

    final_kernel<<<N / 16, 256, 0, stream>>>(F1, W1, b1, W2, b2, out);
}

// Round 4
// 451.217 us; speedup vs baseline: 2.5972x; 1.0260x over previous
//
#include <hip/hip_runtime.h>

#define RN 4
#define XSTRIDE 132   // R + DIN

typedef float  frag_cd __attribute__((ext_vector_type(4)));
typedef short  frag_ab __attribute__((ext_vector_type(8)));

__device__ __forceinline__ ushort f2bf(float f) {
    uint u = __float_as_uint(f);
    u += 0x7FFF + ((u >> 16) & 1);        // RNE
    return (ushort)(u >> 16);
}
__device__ __forceinline__ float bf2f(ushort h) {
    return __uint_as_float(((uint)h) << 16);
}

// ---------------- CSR build ------------------------------------------------
__global__ void count_kernel(const int* __restrict__ ei, int E, int* __restrict__ cnt) {
    int e = blockIdx.x * 256 + threadIdx.x;
    if (e < E) atomicAdd(&cnt[ei[E + e]], 1);
}

__global__ void scanA(const int* __restrict__ cnt, int N, int* __restrict__ bsums) {
    __shared__ int s[256];
    int t = threadIdx.x, n = blockIdx.x * 256 + t;
    s[t] = (n < N) ? cnt[n] : 0;
    __syncthreads();
    for (int off = 128; off > 0; off >>= 1) {
        if (t < off) s[t] += s[t + off];
        __syncthreads();
    }
    if (t == 0) bsums[blockIdx.x] = s[0];
}

__global__ void scanB(int* __restrict__ bsums, int nb) {
    __shared__ int s[256];
    int t = threadIdx.x;
    int v = (t < nb) ? bsums[t] : 0;
    s[t] = v; __syncthreads();
    for (int off = 1; off < 256; off <<= 1) {
        int add = (t >= off) ? s[t - off] : 0;
        __syncthreads();
        s[t] += add;
        __syncthreads();
    }
    if (t < nb) bsums[t] = s[t] - v;   // exclusive
}

__global__ void scanC(const int* __restrict__ cnt, int N,
                      const int* __restrict__ bsums, int* __restrict__ offs) {
    __shared__ int s[256];
    int t = threadIdx.x, n = blockIdx.x * 256 + t;
    int v = (n < N) ? cnt[n] : 0;
    s[t] = v; __syncthreads();
    for (int off = 1; off < 256; off <<= 1) {
        int add = (t >= off) ? s[t - off] : 0;
        __syncthreads();
        s[t] += add;
        __syncthreads();
    }
    if (n < N) {
        offs[n] = bsums[blockIdx.x] + s[t] - v;
        if (n == N - 1) offs[N] = bsums[blockIdx.x] + s[t];
    }
}

__global__ void fill_kernel(const int* __restrict__ ei, int E,
                            const int* __restrict__ offs, int* __restrict__ fc,
                            int* __restrict__ csr) {
    int e = blockIdx.x * 256 + threadIdx.x;
    if (e < E) {
        int dst = ei[E + e];
        int p = offs[dst] + atomicAdd(&fc[dst], 1);
        csr[p] = ei[e];
    }
}

// ---------------- weight pre-convert: fp32 [L][4][K][128] (r<3) ------------
// -> transposed bf16 hi/lo planes [l*3+r][col][K]
__global__ void conv_w(const float* __restrict__ W, ushort* __restrict__ Th,
                       ushort* __restrict__ Tl, int K, int total) {
    int id = blockIdx.x * 256 + threadIdx.x;
    if (id >= total) return;
    int per = K * 128;
    int lr = id / per;              // 0..5  (l*3+r)
    int l = lr / 3, r = lr - l * 3;
    int rem = id - lr * per;
    int k = rem >> 7;
    int col = rem & 127;
    float v = W[(((size_t)l * 4 + r) * K + k) * 128 + col];
    ushort h = f2bf(v);
    size_t dst = ((size_t)lr * 128 + col) * K + k;
    Th[dst] = h;
    Tl[dst] = f2bf(v - bf2f(h));
}

// W1 [128][128] -> [col][k]; W2 [128][40] -> [48][128] zero-padded
__global__ void conv_w12(const float* __restrict__ W1, const float* __restrict__ W2,
                         ushort* __restrict__ W1h, ushort* __restrict__ W1l,
                         ushort* __restrict__ W2h, ushort* __restrict__ W2l) {
    int id = blockIdx.x * 256 + threadIdx.x;
    if (id < 128 * 128) {
        int col = id >> 7, k = id & 127;
        float v = W1[k * 128 + col];
        ushort h = f2bf(v);
        W1h[id] = h; W1l[id] = f2bf(v - bf2f(h));
    } else if (id < 128 * 128 + 48 * 128) {
        int j = id - 128 * 128;
        int col = j >> 7, k = j & 127;
        float v = (col < 40) ? W2[k * 40 + col] : 0.0f;
        ushort h = f2bf(v);
        W2h[j] = h; W2l[j] = f2bf(v - bf2f(h));
    }
}

// x feats -> hi/lo planes [N][128]
__global__ void conv_x(const float* __restrict__ x, ushort* __restrict__ Xh,
                       ushort* __restrict__ Xl, int total) {
    int id = blockIdx.x * 256 + threadIdx.x;
    if (id >= total) return;
    int n = id >> 7, k = id & 127;
    float v = x[(size_t)n * XSTRIDE + RN + k];
    ushort h = f2bf(v);
    Xh[id] = h; Xl[id] = f2bf(v - bf2f(h));
}

// ---------------- aggregate: mean over in-edges of Mb (bf16) -> hi/lo ------
__global__ __launch_bounds__(256) void agg_kernel(
    const int* __restrict__ csr, const int* __restrict__ offs,
    const ushort* __restrict__ Mb, ushort* __restrict__ Sh,
    ushort* __restrict__ Sl, int N)
{
    int node = blockIdx.x * 4 + (threadIdx.x >> 6);
    int lane = threadIdx.x & 63;
    if (node >= N) return;
    int lo = offs[node], hi = offs[node + 1];
    const uint* M32 = (const uint*)Mb;
    float a0 = 0.0f, a1 = 0.0f;
    int e = lo;
    for (; e + 1 < hi; e += 2) {
        uint u = M32[(size_t)csr[e]     * 64 + lane];
        uint v = M32[(size_t)csr[e + 1] * 64 + lane];
        a0 += __uint_as_float(u << 16) + __uint_as_float(v << 16);
        a1 += __uint_as_float(u & 0xFFFF0000u) + __uint_as_float(v & 0xFFFF0000u);
    }
    if (e < hi) {
        uint u = M32[(size_t)csr[e] * 64 + lane];
        a0 += __uint_as_float(u << 16);
        a1 += __uint_as_float(u & 0xFFFF0000u);
    }
    float inv = (hi > lo) ? 1.0f / (float)(hi - lo) : 0.0f;
    float m0 = a0 * inv, m1 = a1 * inv;
    ushort h0 = f2bf(m0), h1 = f2bf(m1);
    ushort l0 = f2bf(m0 - bf2f(h0)), l1 = f2bf(m1 - bf2f(h1));
    ((uint*)Sh)[(size_t)node * 64 + lane] = (uint)h0 | ((uint)h1 << 16);
    ((uint*)Sl)[(size_t)node * 64 + lane] = (uint)l0 | ((uint)l1 << 16);
}

// ---------------- MFMA role-weighted GEMM, zero-LDS-staging ----------------
// out[n][o] = relu( sum_r c_r[n] * ((v[n] @ W_r)[o] + b_r[o]) ), opt row-norm.
// Block 64 nodes x 128 cols, 4 waves; wave w covers cols [32w, 32w+32).
// All operands are global bf16 hi/lo planes; MFMA frags loaded directly.
// 3-term hi/lo split: C += Ah*Bh + Ah*Bl + Al*Bh (~fp32 accuracy).
template<int KV, bool NORM>
__global__ __launch_bounds__(256) void gemm_mfma(
    const float* __restrict__ x,
    const ushort* __restrict__ Fh, const ushort* __restrict__ Fl,  // [N][128]
    const ushort* __restrict__ Sh, const ushort* __restrict__ Sl,  // KV==256
    const ushort* __restrict__ Wh, const ushort* __restrict__ Wl,  // [3][128][KV]
    const float* __restrict__ bias,                                // [4][128]
    ushort* __restrict__ outH, ushort* __restrict__ outL,          // NORM
    ushort* __restrict__ outB)                                     // !NORM (bf16)
{
    __shared__ float cc[64][3];
    __shared__ float red[64][4];

    const int tid = threadIdx.x;
    const int n0 = blockIdx.x * 64;
    const int lane = tid & 63;
    const int wv = tid >> 6;
    const int q = lane >> 4;
    const int lb = lane & 15;
    const int w32 = wv * 32;

    if (tid < 64) {
        const float* xr = x + (size_t)(n0 + tid) * XSTRIDE;
        cc[tid][0] = 2.0f * xr[0];
        cc[tid][1] = xr[1];
        cc[tid][2] = xr[2];
    }
    __syncthreads();

    frag_cd acc[3][4][2];
    #pragma unroll
    for (int r = 0; r < 3; ++r)
        #pragma unroll
        for (int nt = 0; nt < 4; ++nt)
            #pragma unroll
            for (int ct = 0; ct < 2; ++ct)
                acc[r][nt][ct] = (frag_cd){0.f, 0.f, 0.f, 0.f};

    const int NCH = KV / 32;
    #pragma unroll
    for (int ch = 0; ch < NCH; ++ch) {
        const ushort* ah; const ushort* al; int kofs;
        if (KV == 128 || ch < 4) { ah = Fh; al = Fl; kofs = ch * 32; }
        else                     { ah = Sh; al = Sl; kofs = (ch - 4) * 32; }
        frag_ab aH[4], aL[4];
        #pragma unroll
        for (int nt = 0; nt < 4; ++nt) {
            size_t ao = (size_t)(n0 + nt * 16 + lb) * 128 + kofs + q * 8;
            aH[nt] = *(const frag_ab*)(ah + ao);
            aL[nt] = *(const frag_ab*)(al + ao);
        }
        #pragma unroll
        for (int r = 0; r < 3; ++r) {
            #pragma unroll
            for (int ct = 0; ct < 2; ++ct) {
                size_t wo = ((size_t)(r * 128 + w32 + ct * 16 + lb)) * KV + ch * 32 + q * 8;
                frag_ab bH = *(const frag_ab*)(Wh + wo);
                frag_ab bL = *(const frag_ab*)(Wl + wo);
                #pragma unroll
                for (int nt = 0; nt < 4; ++nt) {
                    frag_cd t = acc[r][nt][ct];
                    t = __builtin_amdgcn_mfma_f32_16x16x32_bf16(aH[nt], bH, t, 0, 0, 0);
                    t = __builtin_amdgcn_mfma_f32_16x16x32_bf16(aH[nt], bL, t, 0, 0, 0);
                    t = __builtin_amdgcn_mfma_f32_16x16x32_bf16(aL[nt], bH, t, 0, 0, 0);
                    acc[r][nt][ct] = t;
                }
            }
        }
    }

    // ---- epilogue: combine roles + bias, relu; C/D: col=lane&15, row=q*4+reg
    float vv[4][2][4];   // [nt][ct][rg]
    #pragma unroll
    for (int ct = 0; ct < 2; ++ct) {
        int col = w32 + ct * 16 + lb;
        float b0 = bias[col], b1 = bias[128 + col], b2 = bias[256 + col];
        #pragma unroll
        for (int nt = 0; nt < 4; ++nt) {
            #pragma unroll
            for (int rg = 0; rg < 4; ++rg) {
                int row = nt * 16 + q * 4 + rg;
                float v = cc[row][0] * (acc[0][nt][ct][rg] + b0)
                        + cc[row][1] * (acc[1][nt][ct][rg] + b1)
                        + cc[row][2] * (acc[2][nt][ct][rg] + b2);
                vv[nt][ct][rg] = fmaxf(v, 0.0f);
            }
        }
    }

    if (NORM) {
        // row sum-of-squares: butterfly over lb within q-group, then cross-wave
        #pragma unroll
        for (int nt = 0; nt < 4; ++nt) {
            #pragma unroll
            for (int rg = 0; rg < 4; ++rg) {
                float ss = vv[nt][0][rg] * vv[nt][0][rg] + vv[nt][1][rg] * vv[nt][1][rg];
                #pragma unroll
                for (int m = 1; m < 16; m <<= 1) ss += __shfl_xor(ss, m, 64);
                if (lb == 0) red[nt * 16 + q * 4 + rg][wv] = ss;
            }
        }
        __syncthreads();
        #pragma unroll
        for (int nt = 0; nt < 4; ++nt) {
            #pragma unroll
            for (int rg = 0; rg < 4; ++rg) {
                int row = nt * 16 + q * 4 + rg;
                float t = red[row][0] + red[row][1] + red[row][2] + red[row][3];
                float inv = 1.0f / fmaxf(sqrtf(t), 1e-12f);
                #pragma unroll
                for (int ct = 0; ct < 2; ++ct) {
                    int col = w32 + ct * 16 + lb;
                    float v = vv[nt][ct][rg] * inv;
                    ushort h = f2bf(v);
                    size_t o = (size_t)(n0 + row) * 128 + col;
                    outH[o] = h;
                    outL[o] = f2bf(v - bf2f(h));
                }
            }
        }
    } else {
        #pragma unroll
        for (int nt = 0; nt < 4; ++nt)
            #pragma unroll
            for (int ct = 0; ct < 2; ++ct)
                #pragma unroll
                for (int rg = 0; rg < 4; ++rg) {
                    int row = nt * 16 + q * 4 + rg;
                    int col = w32 + ct * 16 + lb;
                    outB[(size_t)(n0 + row) * 128 + col] = f2bf(vv[nt][ct][rg]);
                }
    }
}

// ---------------- final: z=F@W1+b1; logits=z@W2+b2; log_softmax (MFMA) ------
__global__ __launch_bounds__(256) void final_mfma(
    const ushort* __restrict__ F2h, const ushort* __restrict__ F2l,  // [N][128]
    const ushort* __restrict__ W1h, const ushort* __restrict__ W1l,  // [128][128]
    const float* __restrict__ b1,
    const ushort* __restrict__ W2h, const ushort* __restrict__ W2l,  // [48][128]
    const float* __restrict__ b2,
    float* __restrict__ out)                                         // N x 40
{
    __shared__ ushort Zh[64][136];
    __shared__ ushort Zl[64][136];

    const int tid = threadIdx.x;
    const int n0 = blockIdx.x * 64;
    const int lane = tid & 63;
    const int wv = tid >> 6;
    const int q = lane >> 4;
    const int lb = lane & 15;
    const int w32 = wv * 32;

    // ---- z = F@W1 + b1 : block 64 rows x 128 cols, wave = 32-col slice ----
    frag_cd acc[4][2];
    #pragma unroll
    for (int nt = 0; nt < 4; ++nt)
        #pragma unroll
        for (int ct = 0; ct < 2; ++ct) acc[nt][ct] = (frag_cd){0.f, 0.f, 0.f, 0.f};

    #pragma unroll
    for (int ch = 0; ch < 4; ++ch) {
        frag_ab aH[4], aL[4];
        #pragma unroll
        for (int nt = 0; nt < 4; ++nt) {
            size_t ao = (size_t)(n0 + nt * 16 + lb) * 128 + ch * 32 + q * 8;
            aH[nt] = *(const frag_ab*)(F2h + ao);
            aL[nt] = *(const frag_ab*)(F2l + ao);
        }
        #pragma unroll
        for (int ct = 0; ct < 2; ++ct) {
            size_t wo = (size_t)(w32 + ct * 16 + lb) * 128 + ch * 32 + q * 8;
            frag_ab bH = *(const frag_ab*)(W1h + wo);
            frag_ab bL = *(const frag_ab*)(W1l + wo);
            #pragma unroll
            for (int nt = 0; nt < 4; ++nt) {
                frag_cd t = acc[nt][ct];
                t = __builtin_amdgcn_mfma_f32_16x16x32_bf16(aH[nt], bH, t, 0, 0, 0);
                t = __builtin_amdgcn_mfma_f32_16x16x32_bf16(aH[nt], bL, t, 0, 0, 0);
                t = __builtin_amdgcn_mfma_f32_16x16x32_bf16(aL[nt], bH, t, 0, 0, 0);
                acc[nt][ct] = t;
            }
        }
    }
    // z -> LDS hi/lo (A-layout source for second GEMM)
    #pragma unroll
    for (int ct = 0; ct < 2; ++ct) {
        int col = w32 + ct * 16 + lb;
        float bb = b1[col];
        #pragma unroll
        for (int nt = 0; nt < 4; ++nt)
            #pragma unroll
            for (int rg = 0; rg < 4; ++rg) {
                int row = nt * 16 + q * 4 + rg;
                float v = acc[nt][ct][rg] + bb;
                ushort h = f2bf(v);
                Zh[row][col] = h;
                Zl[row][col] = f2bf(v - bf2f(h));
            }
    }
    __syncthreads();

    // ---- logits = z@W2 + b2 : wave = 16-row tile, 48 cols (40 real) ----
    frag_cd a2[3];
    #pragma unroll
    for (int ct = 0; ct < 3; ++ct) a2[ct] = (frag_cd){0.f, 0.f, 0.f, 0.f};
    #pragma unroll
    for (int ch = 0; ch < 4; ++ch) {
        frag_ab zH = *(const frag_ab*)&Zh[wv * 16 + lb][ch * 32 + q * 8];
        frag_ab zL = *(const frag_ab*)&Zl[wv * 16 + lb][ch * 32 + q * 8];
        #pragma unroll
        for (int ct = 0; ct < 3; ++ct) {
            size_t wo = (size_t)(ct * 16 + lb) * 128 + ch * 32 + q * 8;
            frag_ab bH = *(const frag_ab*)(W2h + wo);
            frag_ab bL = *(const frag_ab*)(W2l + wo);
            frag_cd t = a2[ct];
            t = __builtin_amdgcn_mfma_f32_16x16x32_bf16(zH, bH, t, 0, 0, 0);
            t = __builtin_amdgcn_mfma_f32_16x16x32_bf16(zH, bL, t, 0, 0, 0);
            t = __builtin_amdgcn_mfma_f32_16x16x32_bf16(zL, bH, t, 0, 0, 0);
            a2[ct] = t;
        }
    }

    // ---- log_softmax over 40 cols; lane holds cols {lb, 16+lb, 32+lb} ----
    float lg[3][4];
    #pragma unroll
    for (int ct = 0; ct < 3; ++ct) {
        int col = ct * 16 + lb;
        bool valid = col < 40;
        float bb = valid ? b2[col] : -1e30f;
        #pragma unroll
        for (int rg = 0; rg < 4; ++rg)
            lg[ct][rg] = valid ? (a2[ct][rg] + bb) : -1e30f;
    }
    #pragma unroll
    for (int rg = 0; rg < 4; ++rg) {
        float mx = fmaxf(fmaxf(lg[0][rg], lg[1][rg]), lg[2][rg]);
        #pragma unroll
        for (int m = 1; m < 16; m <<= 1) mx = fmaxf(mx, __shfl_xor(mx, m, 64));
        float sm = __expf(lg[0][rg] - mx) + __expf(lg[1][rg] - mx) + __expf(lg[2][rg] - mx);
        #pragma unroll
        for (int m = 1; m < 16; m <<= 1) sm += __shfl_xor(sm, m, 64);
        float ls = mx + __logf(sm);
        int row = n0 + wv * 16 + q * 4 + rg;
        #pragma unroll
        for (int ct = 0; ct < 3; ++ct) {
            int col = ct * 16 + lb;
            if (col < 40) out[(size_t)row * 40 + col] = lg[ct][rg] - ls;
        }
    }
}

extern "C" void kernel_launch(void* const* d_in, const int* in_sizes, int n_in,
                              void* d_out, int out_size, void* d_ws, size_t ws_size,
                              hipStream_t stream) {
    const float* x  = (const float*)d_in[0];
    const int*   ei = (const int*)d_in[1];
    const float* Wm = (const float*)d_in[2];
    const float* bm = (const float*)d_in[3];
    const float* Wa = (const float*)d_in[4];
    const float* ba = (const float*)d_in[5];
    const float* W1 = (const float*)d_in[6];
    const float* b1 = (const float*)d_in[7];
    const float* W2 = (const float*)d_in[8];
    const float* b2 = (const float*)d_in[9];
    float* out = (float*)d_out;

    const int N = in_sizes[0] / XSTRIDE;   // 40000
    const int E = in_sizes[1] / 2;         // 480000
    const int NB = (N + 255) / 256;        // 157
    const size_t P = (size_t)N * 128;      // plane elements

    // workspace carve (16B-aligned)
    ushort* Mb   = (ushort*)d_ws;          // msg bf16
    ushort* Xh   = Mb + P;                 // x feats hi  (reused as F2h)
    ushort* Xl   = Xh + P;                 // x feats lo  (reused as F2l)
    ushort* Sh   = Xl + P;                 // aggr hi
    ushort* Sl   = Sh + P;                 // aggr lo
    ushort* F1h  = Sl + P;                 // layer-1 out hi
    ushort* F1l  = F1h + P;                // layer-1 out lo
    ushort* WmTh = F1l + P;                // 6*128*128
    ushort* WmTl = WmTh + 6 * 128 * 128;
    ushort* WaTh = WmTl + 6 * 128 * 128;   // 6*128*256
    ushort* WaTl = WaTh + 6 * 128 * 256;
    ushort* W1h  = WaTl + 6 * 128 * 256;   // 128*128
    ushort* W1l  = W1h + 128 * 128;
    ushort* W2h  = W1l + 128 * 128;        // 48*128
    ushort* W2l  = W2h + 48 * 128;
    int* cnt   = (int*)(W2l + 48 * 128);
    int* offs  = cnt + N;
    int* csr   = offs + N + 1;
    int* bsums = csr + E;

    // ---- pre-convert ----
    conv_w<<<(6 * 128 * 128 + 255) / 256, 256, 0, stream>>>(Wm, WmTh, WmTl, 128, 6 * 128 * 128);
    conv_w<<<(6 * 128 * 256 + 255) / 256, 256, 0, stream>>>(Wa, WaTh, WaTl, 256, 6 * 128 * 256);
    conv_w12<<<(128 * 128 + 48 * 128 + 255) / 256, 256, 0, stream>>>(W1, W2, W1h, W1l, W2h, W2l);
    conv_x<<<(N * 128 + 255) / 256, 256, 0, stream>>>(x, Xh, Xl, N * 128);

    // ---- CSR build ----
    hipMemsetAsync(cnt, 0, (size_t)N * sizeof(int), stream);
    count_kernel<<<(E + 255) / 256, 256, 0, stream>>>(ei, E, cnt);
    scanA<<<NB, 256, 0, stream>>>(cnt, N, bsums);
    scanB<<<1, 256, 0, stream>>>(bsums, NB);
    scanC<<<NB, 256, 0, stream>>>(cnt, N, bsums, offs);
    hipMemsetAsync(cnt, 0, (size_t)N * sizeof(int), stream);
    fill_kernel<<<(E + 255) / 256, 256, 0, stream>>>(ei, E, offs, cnt, csr);

    const int gblk = N / 64;               // 625
    for (int l = 0; l < 2; ++l) {
        const ushort* fh = (l == 0) ? Xh : F1h;
        const ushort* fl = (l == 0) ? Xl : F1l;
        ushort* oh = (l == 0) ? F1h : Xh;  // layer-2 output aliases X planes (F2)
        ushort* ol = (l == 0) ? F1l : Xl;

        gemm_mfma<128, false><<<gblk, 256, 0, stream>>>(
            x, fh, fl, nullptr, nullptr,
            WmTh + (size_t)l * 3 * 128 * 128, WmTl + (size_t)l * 3 * 128 * 128,
            bm + (size_t)l * 4 * 128, nullptr, nullptr, Mb);
        agg_kernel<<<(N + 3) / 4, 256, 0, stream>>>(csr, offs, Mb, Sh, Sl, N);
        gemm_mfma<256, true><<<gblk, 256, 0, stream>>>(
            x, fh, fl, Sh, Sl,
            WaTh + (size_t)l * 3 * 128 * 256, WaTl + (size_t)l * 3 * 128 * 256,
            ba + (size_t)l * 4 * 128, oh, ol, nullptr);
    }

    final_mfma<<<gblk, 256, 0, stream>>>(Xh, Xl, W1h, W1l, b1, W2h, W2l, b2, out);
}

// Round 5
// 349.242 us; speedup vs baseline: 3.3555x; 1.2920x over previous
//
#include <hip/hip_runtime.h>
#include <hip/hip_fp16.h>

#define RN 4
#define XSTRIDE 132   // R + DIN

typedef float    frag_cd __attribute__((ext_vector_type(4)));
typedef _Float16 frag_h  __attribute__((ext_vector_type(8)));

// ---------------- CSR build ------------------------------------------------
__global__ void count_kernel(const int* __restrict__ ei, int E, int* __restrict__ cnt) {
    int e = blockIdx.x * 256 + threadIdx.x;
    if (e < E) atomicAdd(&cnt[ei[E + e]], 1);
}

__global__ void scanA(const int* __restrict__ cnt, int N, int* __restrict__ bsums) {
    __shared__ int s[256];
    int t = threadIdx.x, n = blockIdx.x * 256 + t;
    s[t] = (n < N) ? cnt[n] : 0;
    __syncthreads();
    for (int off = 128; off > 0; off >>= 1) {
        if (t < off) s[t] += s[t + off];
        __syncthreads();
    }
    if (t == 0) bsums[blockIdx.x] = s[0];
}

__global__ void scanB(int* __restrict__ bsums, int nb) {
    __shared__ int s[256];
    int t = threadIdx.x;
    int v = (t < nb) ? bsums[t] : 0;
    s[t] = v; __syncthreads();
    for (int off = 1; off < 256; off <<= 1) {
        int add = (t >= off) ? s[t - off] : 0;
        __syncthreads();
        s[t] += add;
        __syncthreads();
    }
    if (t < nb) bsums[t] = s[t] - v;   // exclusive
}

__global__ void scanC(const int* __restrict__ cnt, int N,
                      const int* __restrict__ bsums, int* __restrict__ offs) {
    __shared__ int s[256];
    int t = threadIdx.x, n = blockIdx.x * 256 + t;
    int v = (n < N) ? cnt[n] : 0;
    s[t] = v; __syncthreads();
    for (int off = 1; off < 256; off <<= 1) {
        int add = (t >= off) ? s[t - off] : 0;
        __syncthreads();
        s[t] += add;
        __syncthreads();
    }
    if (n < N) {
        offs[n] = bsums[blockIdx.x] + s[t] - v;
        if (n == N - 1) offs[N] = bsums[blockIdx.x] + s[t];
    }
}

__global__ void fill_kernel(const int* __restrict__ ei, int E,
                            const int* __restrict__ offs, int* __restrict__ fc,
                            int* __restrict__ csr) {
    int e = blockIdx.x * 256 + threadIdx.x;
    if (e < E) {
        int dst = ei[E + e];
        int p = offs[dst] + atomicAdd(&fc[dst], 1);
        csr[p] = ei[e];
    }
}

// ---------------- weight pre-convert: fp32 [L][4][K][128] (r<3) ------------
// -> transposed fp16 planes [l*3+r][col][K]
__global__ void conv_w(const float* __restrict__ W, _Float16* __restrict__ T,
                       int K, int total) {
    int id = blockIdx.x * 256 + threadIdx.x;
    if (id >= total) return;
    int per = K * 128;
    int lr = id / per;              // 0..5  (l*3+r)
    int l = lr / 3, r = lr - l * 3;
    int rem = id - lr * per;
    int k = rem >> 7;
    int col = rem & 127;
    float v = W[(((size_t)l * 4 + r) * K + k) * 128 + col];
    T[((size_t)lr * 128 + col) * K + k] = (_Float16)v;
}

// W1 [128][128] -> [col][k]; W2 [128][40] -> [48][128] zero-padded
__global__ void conv_w12(const float* __restrict__ W1, const float* __restrict__ W2,
                         _Float16* __restrict__ T1, _Float16* __restrict__ T2) {
    int id = blockIdx.x * 256 + threadIdx.x;
    if (id < 128 * 128) {
        int col = id >> 7, k = id & 127;
        T1[id] = (_Float16)W1[k * 128 + col];
    } else if (id < 128 * 128 + 48 * 128) {
        int j = id - 128 * 128;
        int col = j >> 7, k = j & 127;
        T2[j] = (_Float16)((col < 40) ? W2[k * 40 + col] : 0.0f);
    }
}

// x feats -> fp16 plane [N][128]
__global__ void conv_x(const float* __restrict__ x, _Float16* __restrict__ X, int total) {
    int id = blockIdx.x * 256 + threadIdx.x;
    if (id >= total) return;
    int n = id >> 7, k = id & 127;
    X[id] = (_Float16)x[(size_t)n * XSTRIDE + RN + k];
}

// ---------------- aggregate: mean over in-edges of Mb (fp16) -> fp16 -------
__global__ __launch_bounds__(256) void agg_kernel(
    const int* __restrict__ csr, const int* __restrict__ offs,
    const _Float16* __restrict__ Mb, _Float16* __restrict__ S, int N)
{
    int node = blockIdx.x * 4 + (threadIdx.x >> 6);
    int lane = threadIdx.x & 63;
    if (node >= N) return;
    int lo = offs[node], hi = offs[node + 1];
    const __half2* M2 = (const __half2*)Mb;
    float a0 = 0.0f, a1 = 0.0f;
    int e = lo;
    for (; e + 1 < hi; e += 2) {
        float2 u = __half22float2(M2[(size_t)csr[e]     * 64 + lane]);
        float2 v = __half22float2(M2[(size_t)csr[e + 1] * 64 + lane]);
        a0 += u.x + v.x; a1 += u.y + v.y;
    }
    if (e < hi) {
        float2 u = __half22float2(M2[(size_t)csr[e] * 64 + lane]);
        a0 += u.x; a1 += u.y;
    }
    float inv = (hi > lo) ? 1.0f / (float)(hi - lo) : 0.0f;
    ((__half2*)S)[(size_t)node * 64 + lane] =
        __float22half2_rn(make_float2(a0 * inv, a1 * inv));
}

// ---------------- MFMA role-weighted GEMM, fp16 single-term ----------------
// out[n][o] = relu( sum_r c_r[n] * ((v[n] @ W_r)[o] + b_r[o]) ), opt row-norm.
// Block 64 nodes x 128 cols, 4 waves; wave w covers cols [32w, 32w+32).
// Operands are global fp16 planes; MFMA frags loaded directly (no LDS staging).
// fp32 accumulate in MFMA; coef/bias/norm applied in fp32 epilogue.
template<int KV, bool NORM>
__global__ __launch_bounds__(256) void gemm_mfma(
    const float* __restrict__ x,
    const _Float16* __restrict__ Fp,               // [N][128]
    const _Float16* __restrict__ Sp,               // KV==256 only
    const _Float16* __restrict__ W,                // [3][128][KV]
    const float* __restrict__ bias,                // [4][128]
    _Float16* __restrict__ out)                    // [N][128]
{
    __shared__ float cc[64][3];
    __shared__ float red[64][4];

    const int tid = threadIdx.x;
    const int n0 = blockIdx.x * 64;
    const int lane = tid & 63;
    const int wv = tid >> 6;
    const int q = lane >> 4;
    const int lb = lane & 15;
    const int w32 = wv * 32;

    if (tid < 64) {
        const float* xr = x + (size_t)(n0 + tid) * XSTRIDE;
        cc[tid][0] = 2.0f * xr[0];
        cc[tid][1] = xr[1];
        cc[tid][2] = xr[2];
    }
    __syncthreads();

    frag_cd acc[3][4][2];
    #pragma unroll
    for (int r = 0; r < 3; ++r)
        #pragma unroll
        for (int nt = 0; nt < 4; ++nt)
            #pragma unroll
            for (int ct = 0; ct < 2; ++ct)
                acc[r][nt][ct] = (frag_cd){0.f, 0.f, 0.f, 0.f};

    const int NCH = KV / 32;
    #pragma unroll
    for (int ch = 0; ch < NCH; ++ch) {
        const _Float16* ap; int kofs;
        if (KV == 128 || ch < 4) { ap = Fp; kofs = ch * 32; }
        else                     { ap = Sp; kofs = (ch - 4) * 32; }
        frag_h aF[4];
        #pragma unroll
        for (int nt = 0; nt < 4; ++nt)
            aF[nt] = *(const frag_h*)(ap + (size_t)(n0 + nt * 16 + lb) * 128 + kofs + q * 8);
        #pragma unroll
        for (int r = 0; r < 3; ++r) {
            #pragma unroll
            for (int ct = 0; ct < 2; ++ct) {
                frag_h bF = *(const frag_h*)(
                    W + ((size_t)(r * 128 + w32 + ct * 16 + lb)) * KV + ch * 32 + q * 8);
                #pragma unroll
                for (int nt = 0; nt < 4; ++nt)
                    acc[r][nt][ct] = __builtin_amdgcn_mfma_f32_16x16x32_f16(
                        aF[nt], bF, acc[r][nt][ct], 0, 0, 0);
            }
        }
    }

    // ---- epilogue: combine roles + bias, relu; C/D: col=lane&15, row=q*4+reg
    float vv[4][2][4];   // [nt][ct][rg]
    #pragma unroll
    for (int ct = 0; ct < 2; ++ct) {
        int col = w32 + ct * 16 + lb;
        float b0 = bias[col], b1 = bias[128 + col], b2 = bias[256 + col];
        #pragma unroll
        for (int nt = 0; nt < 4; ++nt) {
            #pragma unroll
            for (int rg = 0; rg < 4; ++rg) {
                int row = nt * 16 + q * 4 + rg;
                float v = cc[row][0] * (acc[0][nt][ct][rg] + b0)
                        + cc[row][1] * (acc[1][nt][ct][rg] + b1)
                        + cc[row][2] * (acc[2][nt][ct][rg] + b2);
                vv[nt][ct][rg] = fmaxf(v, 0.0f);
            }
        }
    }

    if (NORM) {
        #pragma unroll
        for (int nt = 0; nt < 4; ++nt) {
            #pragma unroll
            for (int rg = 0; rg < 4; ++rg) {
                float ss = vv[nt][0][rg] * vv[nt][0][rg] + vv[nt][1][rg] * vv[nt][1][rg];
                #pragma unroll
                for (int m = 1; m < 16; m <<= 1) ss += __shfl_xor(ss, m, 64);
                if (lb == 0) red[nt * 16 + q * 4 + rg][wv] = ss;
            }
        }
        __syncthreads();
        #pragma unroll
        for (int nt = 0; nt < 4; ++nt) {
            #pragma unroll
            for (int rg = 0; rg < 4; ++rg) {
                int row = nt * 16 + q * 4 + rg;
                float t = red[row][0] + red[row][1] + red[row][2] + red[row][3];
                float inv = 1.0f / fmaxf(sqrtf(t), 1e-12f);
                #pragma unroll
                for (int ct = 0; ct < 2; ++ct) {
                    int col = w32 + ct * 16 + lb;
                    out[(size_t)(n0 + row) * 128 + col] = (_Float16)(vv[nt][ct][rg] * inv);
                }
            }
        }
    } else {
        #pragma unroll
        for (int nt = 0; nt < 4; ++nt)
            #pragma unroll
            for (int ct = 0; ct < 2; ++ct)
                #pragma unroll
                for (int rg = 0; rg < 4; ++rg) {
                    int row = nt * 16 + q * 4 + rg;
                    int col = w32 + ct * 16 + lb;
                    out[(size_t)(n0 + row) * 128 + col] = (_Float16)vv[nt][ct][rg];
                }
    }
}

// ---------------- final: z=F@W1+b1; logits=z@W2+b2; log_softmax (MFMA) ------
__global__ __launch_bounds__(256) void final_mfma(
    const _Float16* __restrict__ F2,               // [N][128]
    const _Float16* __restrict__ W1T,              // [128][128] ([col][k])
    const float* __restrict__ b1,
    const _Float16* __restrict__ W2T,              // [48][128] zero-padded
    const float* __restrict__ b2,
    float* __restrict__ out)                       // N x 40
{
    __shared__ _Float16 Z[64][136];

    const int tid = threadIdx.x;
    const int n0 = blockIdx.x * 64;
    const int lane = tid & 63;
    const int wv = tid >> 6;
    const int q = lane >> 4;
    const int lb = lane & 15;
    const int w32 = wv * 32;

    // ---- z = F@W1 + b1 : block 64 rows x 128 cols, wave = 32-col slice ----
    frag_cd acc[4][2];
    #pragma unroll
    for (int nt = 0; nt < 4; ++nt)
        #pragma unroll
        for (int ct = 0; ct < 2; ++ct) acc[nt][ct] = (frag_cd){0.f, 0.f, 0.f, 0.f};

    #pragma unroll
    for (int ch = 0; ch < 4; ++ch) {
        frag_h aF[4];
        #pragma unroll
        for (int nt = 0; nt < 4; ++nt)
            aF[nt] = *(const frag_h*)(F2 + (size_t)(n0 + nt * 16 + lb) * 128 + ch * 32 + q * 8);
        #pragma unroll
        for (int ct = 0; ct < 2; ++ct) {
            frag_h bF = *(const frag_h*)(W1T + (size_t)(w32 + ct * 16 + lb) * 128 + ch * 32 + q * 8);
            #pragma unroll
            for (int nt = 0; nt < 4; ++nt)
                acc[nt][ct] = __builtin_amdgcn_mfma_f32_16x16x32_f16(aF[nt], bF, acc[nt][ct], 0, 0, 0);
        }
    }
    // z -> LDS fp16 (A-layout source for second GEMM)
    #pragma unroll
    for (int ct = 0; ct < 2; ++ct) {
        int col = w32 + ct * 16 + lb;
        float bb = b1[col];
        #pragma unroll
        for (int nt = 0; nt < 4; ++nt)
            #pragma unroll
            for (int rg = 0; rg < 4; ++rg)
                Z[nt * 16 + q * 4 + rg][col] = (_Float16)(acc[nt][ct][rg] + bb);
    }
    __syncthreads();

    // ---- logits = z@W2 + b2 : wave = 16-row tile, 48 cols (40 real) ----
    frag_cd a2[3];
    #pragma unroll
    for (int ct = 0; ct < 3; ++ct) a2[ct] = (frag_cd){0.f, 0.f, 0.f, 0.f};
    #pragma unroll
    for (int ch = 0; ch < 4; ++ch) {
        frag_h zF = *(const frag_h*)&Z[wv * 16 + lb][ch * 32 + q * 8];
        #pragma unroll
        for (int ct = 0; ct < 3; ++ct) {
            frag_h bF = *(const frag_h*)(W2T + (size_t)(ct * 16 + lb) * 128 + ch * 32 + q * 8);
            a2[ct] = __builtin_amdgcn_mfma_f32_16x16x32_f16(zF, bF, a2[ct], 0, 0, 0);
        }
    }

    // ---- log_softmax over 40 cols; lane holds cols {lb, 16+lb, 32+lb} ----
    float lg[3][4];
    #pragma unroll
    for (int ct = 0; ct < 3; ++ct) {
        int col = ct * 16 + lb;
        bool valid = col < 40;
        float bb = valid ? b2[col] : -1e30f;
        #pragma unroll
        for (int rg = 0; rg < 4; ++rg)
            lg[ct][rg] = valid ? (a2[ct][rg] + bb) : -1e30f;
    }
    #pragma unroll
    for (int rg = 0; rg < 4; ++rg) {
        float mx = fmaxf(fmaxf(lg[0][rg], lg[1][rg]), lg[2][rg]);
        #pragma unroll
        for (int m = 1; m < 16; m <<= 1) mx = fmaxf(mx, __shfl_xor(mx, m, 64));
        float sm = __expf(lg[0][rg] - mx) + __expf(lg[1][rg] - mx) + __expf(lg[2][rg] - mx);
        #pragma unroll
        for (int m = 1; m < 16; m <<= 1) sm += __shfl_xor(sm, m, 64);
        float ls = mx + __logf(sm);
        int row = n0 + wv * 16 + q * 4 + rg;
        #pragma unroll
        for (int ct = 0; ct < 3; ++ct) {
            int col = ct * 16 + lb;
            if (col < 40) out[(size_t)row * 40 + col] = lg[ct][rg] - ls;
        }
    }
}

extern "C" void kernel_launch(void* const* d_in, const int* in_sizes, int n_in,
                              void* d_out, int out_size, void* d_ws, size_t ws_size,
                              hipStream_t stream) {
    const float* x  = (const float*)d_in[0];
    const int*   ei = (const int*)d_in[1];
    const float* Wm = (const float*)d_in[2];
    const float* bm = (const float*)d_in[3];
    const float* Wa = (const float*)d_in[4];
    const float* ba = (const float*)d_in[5];
    const float* W1 = (const float*)d_in[6];
    const float* b1 = (const float*)d_in[7];
    const float* W2 = (const float*)d_in[8];
    const float* b2 = (const float*)d_in[9];
    float* out = (float*)d_out;

    const int N = in_sizes[0] / XSTRIDE;   // 40000
    const int E = in_sizes[1] / 2;         // 480000
    const int NB = (N + 255) / 256;        // 157
    const size_t P = (size_t)N * 128;      // plane elements

    // workspace carve (16B-aligned)
    _Float16* Mb  = (_Float16*)d_ws;       // msg fp16
    _Float16* X   = Mb + P;                // x feats (reused as F2 for final)
    _Float16* S   = X + P;                 // aggr
    _Float16* F1  = S + P;                 // layer-1 out
    _Float16* WmT = F1 + P;                // 6*128*128
    _Float16* WaT = WmT + 6 * 128 * 128;   // 6*128*256
    _Float16* W1T = WaT + 6 * 128 * 256;   // 128*128
    _Float16* W2T = W1T + 128 * 128;       // 48*128
    int* cnt   = (int*)(W2T + 48 * 128);
    int* offs  = cnt + N;
    int* csr   = offs + N + 1;
    int* bsums = csr + E;

    // ---- pre-convert ----
    conv_w<<<(6 * 128 * 128 + 255) / 256, 256, 0, stream>>>(Wm, WmT, 128, 6 * 128 * 128);
    conv_w<<<(6 * 128 * 256 + 255) / 256, 256, 0, stream>>>(Wa, WaT, 256, 6 * 128 * 256);
    conv_w12<<<(128 * 128 + 48 * 128 + 255) / 256, 256, 0, stream>>>(W1, W2, W1T, W2T);
    conv_x<<<(N * 128 + 255) / 256, 256, 0, stream>>>(x, X, N * 128);

    // ---- CSR build ----
    hipMemsetAsync(cnt, 0, (size_t)N * sizeof(int), stream);
    count_kernel<<<(E + 255) / 256, 256, 0, stream>>>(ei, E, cnt);
    scanA<<<NB, 256, 0, stream>>>(cnt, N, bsums);
    scanB<<<1, 256, 0, stream>>>(bsums, NB);
    scanC<<<NB, 256, 0, stream>>>(cnt, N, bsums, offs);
    hipMemsetAsync(cnt, 0, (size_t)N * sizeof(int), stream);
    fill_kernel<<<(E + 255) / 256, 256, 0, stream>>>(ei, E, offs, cnt, csr);

    const int gblk = N / 64;               // 625
    for (int l = 0; l < 2; ++l) {
        const _Float16* fp = (l == 0) ? X : F1;
        _Float16* o = (l == 0) ? F1 : X;   // layer-2 output aliases X (becomes F2)

        gemm_mfma<128, false><<<gblk, 256, 0, stream>>>(
            x, fp, nullptr,
            WmT + (size_t)l * 3 * 128 * 128, bm + (size_t)l * 4 * 128, Mb);
        agg_kernel<<<(N + 3) / 4, 256, 0, stream>>>(csr, offs, Mb, S, N);
        gemm_mfma<256, true><<<gblk, 256, 0, stream>>>(
            x, fp, S,
            WaT + (size_t)l * 3 * 128 * 256, ba + (size_t)l * 4 * 128, o);
    }

    final_mfma<<<gblk, 256, 0, stream>>>(X, W1T, b1, W2T, b2, out);
}